// Round 1
// baseline (189.900 us; speedup 1.0000x reference)
//
#include <hip/hip_runtime.h>

#define GRIDN  256
#define NPTS   128
#define NBATCH 64

// Scale to [0,255] with clip, matching jnp.clip(p*255, 0, 255).
__device__ __forceinline__ float2 scale_clip(float2 p) {
    return make_float2(fminf(fmaxf(p.x * 255.0f, 0.0f), 255.0f),
                       fminf(fmaxf(p.y * 255.0f, 0.0f), 255.0f));
}

// Coverage rule derived from the reference's sort+pair+floor logic:
// pixel x covered  <=>  exists even m in [max(0,B-1), A-1],
// where A = #{xint < x+1}, B = #{xint < x}.
__device__ __forceinline__ int covered(int A, int B) {
    int hi = A - 1;
    int lo = (B - 1) > 0 ? (B - 1) : 0;
    return (A > 0) && ((hi & ~1) >= lo);
}

__global__ __launch_bounds__(256) void fill_dice_kernel(
    const float* __restrict__ points,   // (64,128,1,2)
    const float* __restrict__ dmap,     // (64,256,256,1)
    unsigned int* __restrict__ acc)     // (64,3): inter, t, q
{
#pragma clang fp contract(off)
    __shared__ float xlds[4][NPTS];     // per-wave crossing buffer

    const int wave = threadIdx.x >> 6;
    const int lane = threadIdx.x & 63;
    const int blk  = blockIdx.x;        // 0..4095
    const int b    = blk >> 6;          // batch
    const int y    = (blk & 63) * 4 + wave;
    const float yf = (float)y;

    const float* pb = points + b * NPTS * 2;

    // Each lane owns edges j0=2*lane, j1=2*lane+1; edge j = (p[j], p[j-1]).
    const int j0 = 2 * lane;
    const int j1 = j0 + 1;
    const int jm = (j0 + NPTS - 1) & (NPTS - 1);

    float2 Pm = scale_clip(*(const float2*)(pb + jm * 2));
    float2 P0 = scale_clip(*(const float2*)(pb + j0 * 2));
    float2 P1 = scale_clip(*(const float2*)(pb + j1 * 2));

    // Half-open crossing rule, exactly as reference.
    const bool c0 = (P0.y < yf && Pm.y >= yf) || (Pm.y < yf && P0.y >= yf);
    const bool c1 = (P1.y < yf && P0.y >= yf) || (P0.y < yf && P1.y >= yf);

    // Intersection x (only meaningful when crossing; denom != 0 then).
    const float xi0 = P0.x + (yf - P0.y) / (Pm.y - P0.y) * (Pm.x - P0.x);
    const float xi1 = P1.x + (yf - P1.y) / (P0.y - P1.y) * (P0.x - P1.x);

    // Ballot-compact crossings into LDS (order irrelevant: we only count ranks).
    const unsigned long long bm0 = __ballot(c0);
    const unsigned long long bm1 = __ballot(c1);
    const unsigned long long lt  = (1ull << lane) - 1ull;
    const int n0  = __popcll(bm0);
    const int cnt = n0 + __popcll(bm1);
    if (c0) xlds[wave][__popcll(bm0 & lt)] = xi0;
    if (c1) xlds[wave][n0 + __popcll(bm1 & lt)] = xi1;
    __syncthreads();

    // 4 pixels per lane; coalesced float4 dmap row read.
    const int px = lane * 4;
    const float4 dv = *(const float4*)(dmap + (size_t)((b * GRIDN + y) * GRIDN + px));
    const int q0 = (dv.x * 255.0f <= 127.0f);
    const int q1 = (dv.y * 255.0f <= 127.0f);
    const int q2 = (dv.z * 255.0f <= 127.0f);
    const int q3 = (dv.w * 255.0f <= 127.0f);

    const float f0 = (float)px;
    const float f1 = (float)(px + 1);
    const float f2 = (float)(px + 2);
    const float f3 = (float)(px + 3);
    const float f4 = (float)(px + 4);

    int C0 = 0, C1 = 0, C2 = 0, C3 = 0, C4 = 0;
    const float* wl = xlds[wave];
    for (int i = 0; i < cnt; ++i) {      // cnt is wave-uniform; LDS broadcast read
        const float v = wl[i];
        C0 += (v < f0); C1 += (v < f1); C2 += (v < f2);
        C3 += (v < f3); C4 += (v < f4);
    }

    const int v0 = covered(C1, C0);
    const int v1 = covered(C2, C1);
    const int v2 = covered(C3, C2);
    const int v3 = covered(C4, C3);

    const int t  = v0 + v1 + v2 + v3;
    const int it = v0 * q0 + v1 * q1 + v2 * q2 + v3 * q3;
    const int q  = q0 + q1 + q2 + q3;

    // Per-lane sums fit in 10 bits after the 64-lane reduce (<= 256 each).
    int packed = it | (t << 10) | (q << 20);
#pragma unroll
    for (int off = 32; off; off >>= 1) packed += __shfl_xor(packed, off);

    if (lane == 0) {
        atomicAdd(&acc[b * 3 + 0], (unsigned)( packed        & 1023));
        atomicAdd(&acc[b * 3 + 1], (unsigned)((packed >> 10) & 1023));
        atomicAdd(&acc[b * 3 + 2], (unsigned)((packed >> 20) & 1023));
    }
}

__global__ void finalize_kernel(const unsigned int* __restrict__ acc,
                                float* __restrict__ out)
{
    const int lane = threadIdx.x;   // 64 threads, one per batch
    const float I = (float)acc[lane * 3 + 0];
    const float T = (float)acc[lane * 3 + 1];
    const float Q = (float)acc[lane * 3 + 2];
    const float dice = (2.0f * I + 1e-6f) / (T + Q + 1e-6f);
    float loss = 1.0f - dice;
#pragma unroll
    for (int off = 32; off; off >>= 1) loss += __shfl_xor(loss, off);
    if (lane == 0) out[0] = loss * (1.0f / 64.0f);
}

extern "C" void kernel_launch(void* const* d_in, const int* in_sizes, int n_in,
                              void* d_out, int out_size, void* d_ws, size_t ws_size,
                              hipStream_t stream)
{
    const float* points = (const float*)d_in[0];   // (64,128,1,2)
    const float* dmap   = (const float*)d_in[1];   // (64,256,256,1)
    float* out          = (float*)d_out;
    unsigned int* acc   = (unsigned int*)d_ws;     // 64*3 uints

    hipMemsetAsync(acc, 0, NBATCH * 3 * sizeof(unsigned int), stream);
    fill_dice_kernel<<<dim3(4096), dim3(256), 0, stream>>>(points, dmap, acc);
    finalize_kernel<<<dim3(1), dim3(64), 0, stream>>>(acc, out);
}

// Round 3
// 82.145 us; speedup vs baseline: 2.3118x; 2.3118x over previous
//
#include <hip/hip_runtime.h>

#define GRIDN  256
#define NPTS   128
#define NBATCH 64

// Scale to [0,255] with clip, matching jnp.clip(p*255, 0, 255).
__device__ __forceinline__ float2 scale_clip(float2 p) {
    return make_float2(fminf(fmaxf(p.x * 255.0f, 0.0f), 255.0f),
                       fminf(fmaxf(p.y * 255.0f, 0.0f), 255.0f));
}

// Coverage rule derived from the reference's sort+pair+floor logic:
// pixel x covered  <=>  exists even m in [max(0,B-1), A-1],
// where A = #{xint < x+1}, B = #{xint < x}.
__device__ __forceinline__ int covered(int A, int B) {
    const int hi = (A - 1) & ~1;
    const int lo = (B - 1) > 0 ? (B - 1) : 0;
    return (A > 0) && (hi >= lo);
}

__global__ __launch_bounds__(256) void fill_dice_kernel(
    const float* __restrict__ points,   // (64,128,1,2)
    const float* __restrict__ dmap,     // (64,256,256,1)
    unsigned int* __restrict__ acc)     // (64,3): inter, t, q
{
#pragma clang fp contract(off)
    __shared__ unsigned int hist[4][GRIDN];   // per-wave crossing histogram (4 KB)
    __shared__ int psum[4][3];                // per-wave partial sums

    const int wave = threadIdx.x >> 6;
    const int lane = threadIdx.x & 63;
    const int blk  = blockIdx.x;        // 0..4095
    const int b    = blk >> 6;          // batch
    const int y    = (blk & 63) * 4 + wave;
    const float yf = (float)y;

    // Zero this wave's histogram (aligned 16B per lane).
    *(uint4*)&hist[wave][lane * 4] = make_uint4(0u, 0u, 0u, 0u);

    const float* pb = points + b * NPTS * 2;

    // Each lane owns edges j0=2*lane, j1=2*lane+1; edge j = (p[j], p[j-1]).
    const int j0 = 2 * lane;
    const int j1 = j0 + 1;
    const int jm = (j0 + NPTS - 1) & (NPTS - 1);

    const float2 Pm = scale_clip(*(const float2*)(pb + jm * 2));
    const float2 P0 = scale_clip(*(const float2*)(pb + j0 * 2));
    const float2 P1 = scale_clip(*(const float2*)(pb + j1 * 2));

    // Half-open crossing rule, exactly as reference.
    const bool c0 = (P0.y < yf && Pm.y >= yf) || (Pm.y < yf && P0.y >= yf);
    const bool c1 = (P1.y < yf && P0.y >= yf) || (P0.y < yf && P1.y >= yf);

    // Intersection x, identical fp order to the reference (contract off).
    const float xi0 = P0.x + (yf - P0.y) / (Pm.y - P0.y) * (Pm.x - P0.x);
    const float xi1 = P1.x + (yf - P1.y) / (P0.y - P1.y) * (P0.x - P1.x);

    // Issue the dmap row read early (coalesced float4) to overlap latency.
    const int px = lane * 4;
    const float4 dv = *(const float4*)(dmap + (size_t)((b * GRIDN + y) * GRIDN + px));

    // Rounding-edge negatives counted exactly, excluded from the histogram.
    const int neg = __popcll(__ballot(c0 && xi0 < 0.0f))
                  + __popcll(__ballot(c1 && xi1 < 0.0f));

    __syncthreads();   // histogram zeroed

    if (c0 && xi0 >= 0.0f) atomicAdd(&hist[wave][min((int)xi0, 255)], 1u);
    if (c1 && xi1 >= 0.0f) atomicAdd(&hist[wave][min((int)xi1, 255)], 1u);

    __syncthreads();   // histogram populated

    // Lane i owns bins 4i..4i+3; C(x) = neg + prefix of hist below x.
    const uint4 hv = *(const uint4*)&hist[wave][lane * 4];
    const int h0 = hv.x, h1 = hv.y, h2 = hv.z, h3 = hv.w;
    const int s = h0 + h1 + h2 + h3;
    int incl = s;
#pragma unroll
    for (int off = 1; off < 64; off <<= 1) {
        const int t = __shfl_up(incl, off);
        if (lane >= off) incl += t;
    }
    const int C0 = neg + incl - s;          // C(4i)   (exclusive scan)
    const int C1 = C0 + h0;                 // C(4i+1)
    const int C2 = C1 + h1;
    const int C3 = C2 + h2;
    const int C4 = C3 + h3;                 // C(4i+4)

    const int q0 = (dv.x * 255.0f <= 127.0f);
    const int q1 = (dv.y * 255.0f <= 127.0f);
    const int q2 = (dv.z * 255.0f <= 127.0f);
    const int q3 = (dv.w * 255.0f <= 127.0f);

    const int v0 = covered(C1, C0);
    const int v1 = covered(C2, C1);
    const int v2 = covered(C3, C2);
    const int v3 = covered(C4, C3);

    const int t_  = v0 + v1 + v2 + v3;
    const int it_ = v0 * q0 + v1 * q1 + v2 * q2 + v3 * q3;
    const int q_  = q0 + q1 + q2 + q3;

    // Per-wave reduce (fields <= 256 each, fit in 10 bits).
    int packed = it_ | (t_ << 10) | (q_ << 20);
#pragma unroll
    for (int off = 32; off; off >>= 1) packed += __shfl_xor(packed, off);

    if (lane == 0) {
        psum[wave][0] =  packed        & 1023;
        psum[wave][1] = (packed >> 10) & 1023;
        psum[wave][2] = (packed >> 20) & 1023;
    }
    __syncthreads();

    if (threadIdx.x < 3) {
        const int i = threadIdx.x;
        const int sum = psum[0][i] + psum[1][i] + psum[2][i] + psum[3][i];
        atomicAdd(&acc[b * 3 + i], (unsigned)sum);
    }
}

__global__ void finalize_kernel(const unsigned int* __restrict__ acc,
                                float* __restrict__ out)
{
    const int lane = threadIdx.x;   // 64 threads, one per batch
    const float I = (float)acc[lane * 3 + 0];
    const float T = (float)acc[lane * 3 + 1];
    const float Q = (float)acc[lane * 3 + 2];
    const float dice = (2.0f * I + 1e-6f) / (T + Q + 1e-6f);
    float loss = 1.0f - dice;
#pragma unroll
    for (int off = 32; off; off >>= 1) loss += __shfl_xor(loss, off);
    if (lane == 0) out[0] = loss * (1.0f / 64.0f);
}

extern "C" void kernel_launch(void* const* d_in, const int* in_sizes, int n_in,
                              void* d_out, int out_size, void* d_ws, size_t ws_size,
                              hipStream_t stream)
{
    const float* points = (const float*)d_in[0];   // (64,128,1,2)
    const float* dmap   = (const float*)d_in[1];   // (64,256,256,1)
    float* out          = (float*)d_out;
    unsigned int* acc   = (unsigned int*)d_ws;     // 64*3 uints

    hipMemsetAsync(acc, 0, NBATCH * 3 * sizeof(unsigned int), stream);
    fill_dice_kernel<<<dim3(4096), dim3(256), 0, stream>>>(points, dmap, acc);
    finalize_kernel<<<dim3(1), dim3(64), 0, stream>>>(acc, out);
}

// Round 8
// 69.772 us; speedup vs baseline: 2.7217x; 1.1773x over previous
//
#include <hip/hip_runtime.h>

#define GRIDN  256
#define NPTS   128
#define NBATCH 64
#define NBLK   1024   // 64 batches x 16 ygroups; 4 waves/block, 4 scanlines/wave

__device__ __forceinline__ float clip255(float v) {
    return fminf(fmaxf(v * 255.0f, 0.0f), 255.0f);
}

__global__ __launch_bounds__(256) void fill_dice_kernel(
    const float* __restrict__ points,   // (64,128,1,2)
    const float* __restrict__ dmap,     // (64,256,256,1)
    uint4* __restrict__ partials)       // (1024): {inter, t, q, 0} per block
{
#pragma clang fp contract(off)
    // Packed histogram: byte k of bin i = #crossings with floor==i on scanline ybase+k.
    // Wave-private -> no barriers needed around it. Counts <=128/byte: no carry.
    __shared__ unsigned int hist[4][GRIDN];
    __shared__ unsigned long long psum[4];

    const int wave  = threadIdx.x >> 6;
    const int lane  = threadIdx.x & 63;
    const int blk   = blockIdx.x;
    const int b     = blk >> 4;          // batch
    const int ybase = (blk & 15) * 16 + wave * 4;

    // dmap rows: issue earliest (4 coalesced b128 loads, consumed last).
    const float* drow = dmap + (size_t)(b * GRIDN + ybase) * GRIDN + lane * 4;
    const float4 dv0 = *(const float4*)(drow);
    const float4 dv1 = *(const float4*)(drow + GRIDN);
    const float4 dv2 = *(const float4*)(drow + 2 * GRIDN);
    const float4 dv3 = *(const float4*)(drow + 3 * GRIDN);

    // Points 2l, 2l+1 via one coalesced float4; Pm = point (2l-1) = P1 of lane l-1 (wrap).
    const float4 pv = *(const float4*)(points + b * NPTS * 2 + lane * 4);
    const float p0x = clip255(pv.x), p0y = clip255(pv.y);
    const float p1x = clip255(pv.z), p1y = clip255(pv.w);
    const int   src = (lane + 63) & 63;
    const float pmx = __shfl(p1x, src);
    const float pmy = __shfl(p1y, src);

    // Zero this wave's packed histogram; ensure it lands before the atomics.
    *(uint4*)&hist[wave][lane * 4] = make_uint4(0u, 0u, 0u, 0u);
    asm volatile("s_waitcnt lgkmcnt(0)" ::: "memory");

    // k-independent edge deltas (reference order preserved for xi itself).
    const float d0y = pmy - p0y, d0x = pmx - p0x;   // edge (p[2l], p[2l-1])
    const float d1y = p0y - p1y, d1x = p0x - p1x;   // edge (p[2l+1], p[2l])

    int neg0, neg1, neg2, neg3;
#define CROSS_K(k, negk)                                                          \
    {                                                                             \
        const float yf = (float)(ybase + (k));                                    \
        const bool c0 = (p0y < yf && pmy >= yf) || (pmy < yf && p0y >= yf);       \
        const bool c1 = (p1y < yf && p0y >= yf) || (p0y < yf && p1y >= yf);       \
        const float xi0 = p0x + (yf - p0y) / d0y * d0x;                           \
        const float xi1 = p1x + (yf - p1y) / d1y * d1x;                           \
        negk = __popcll(__ballot(c0 && xi0 < 0.0f))                               \
             + __popcll(__ballot(c1 && xi1 < 0.0f));                              \
        const unsigned int add = 1u << (8 * (k));                                 \
        if (c0 && xi0 >= 0.0f) atomicAdd(&hist[wave][min((int)xi0, 255)], add);   \
        if (c1 && xi1 >= 0.0f) atomicAdd(&hist[wave][min((int)xi1, 255)], add);   \
    }
    CROSS_K(0, neg0) CROSS_K(1, neg1) CROSS_K(2, neg2) CROSS_K(3, neg3)
#undef CROSS_K

    // Drain the wave's own atomics, then read back packed bins (lane owns 4i..4i+3).
    asm volatile("s_waitcnt lgkmcnt(0)" ::: "memory");
    const uint4 hv = *(const uint4*)&hist[wave][lane * 4];

    // One packed scan serves all 4 scanlines (per-byte prefix <=128, no carry).
    const unsigned int s4 = hv.x + hv.y + hv.z + hv.w;
    unsigned int incl = s4;
#pragma unroll
    for (int off = 1; off < 64; off <<= 1) {
        const unsigned int t = __shfl_up(incl, off);
        if (lane >= off) incl += t;
    }
    const unsigned int excl = incl - s4;    // packed C(4*lane) minus negatives

    // Coverage: v(x) = (C(x) odd) | (bin(x) != 0)  -- exact rewrite of sort/pair/floor.
    int it_ = 0, t_ = 0, q_ = 0;
#define PIX_K(k, negk, dvk)                                                       \
    {                                                                             \
        const int C0 = (int)((excl >> (8 * (k))) & 255u) + negk;                  \
        const int h0 = (int)((hv.x >> (8 * (k))) & 255u);                         \
        const int h1 = (int)((hv.y >> (8 * (k))) & 255u);                         \
        const int h2 = (int)((hv.z >> (8 * (k))) & 255u);                         \
        const int h3 = (int)((hv.w >> (8 * (k))) & 255u);                         \
        const int C1 = C0 + h0, C2 = C1 + h1, C3 = C2 + h2;                       \
        const int v0 = (C0 & 1) | (h0 != 0);                                      \
        const int v1 = (C1 & 1) | (h1 != 0);                                      \
        const int v2 = (C2 & 1) | (h2 != 0);                                      \
        const int v3 = (C3 & 1) | (h3 != 0);                                      \
        const int q0 = (dvk.x * 255.0f <= 127.0f);                                \
        const int q1 = (dvk.y * 255.0f <= 127.0f);                                \
        const int q2 = (dvk.z * 255.0f <= 127.0f);                                \
        const int q3 = (dvk.w * 255.0f <= 127.0f);                                \
        t_  += v0 + v1 + v2 + v3;                                                 \
        q_  += q0 + q1 + q2 + q3;                                                 \
        it_ += v0 * q0 + v1 * q1 + v2 * q2 + v3 * q3;                             \
    }
    PIX_K(0, neg0, dv0) PIX_K(1, neg1, dv1) PIX_K(2, neg2, dv2) PIX_K(3, neg3, dv3)
#undef PIX_K

    // Wave reduce (fields <=16/lane -> <=1024/wave -> 20-bit fields in 64 bits).
    unsigned long long packed = (unsigned long long)it_
                              | ((unsigned long long)t_ << 20)
                              | ((unsigned long long)q_ << 40);
#pragma unroll
    for (int off = 32; off; off >>= 1) packed += __shfl_xor(packed, off);

    if (lane == 0) psum[wave] = packed;
    __syncthreads();                       // the only block-wide barrier
    if (threadIdx.x == 0) {
        const unsigned long long tot = psum[0] + psum[1] + psum[2] + psum[3];
        partials[blk] = make_uint4((unsigned)(tot & 0xFFFFFu),
                                   (unsigned)((tot >> 20) & 0xFFFFFu),
                                   (unsigned)((tot >> 40) & 0xFFFFFu), 0u);
    }
}

__global__ void finalize_kernel(const uint4* __restrict__ partials,
                                float* __restrict__ out)
{
    const int b = threadIdx.x;   // 64 threads, one per batch
    unsigned int I = 0, T = 0, Q = 0;
#pragma unroll
    for (int g = 0; g < 16; ++g) {
        const uint4 p = partials[b * 16 + g];
        I += p.x; T += p.y; Q += p.z;
    }
    const float dice = (2.0f * (float)I + 1e-6f) / ((float)T + (float)Q + 1e-6f);
    float loss = 1.0f - dice;
#pragma unroll
    for (int off = 32; off; off >>= 1) loss += __shfl_xor(loss, off);
    if (b == 0) out[0] = loss * (1.0f / 64.0f);
}

extern "C" void kernel_launch(void* const* d_in, const int* in_sizes, int n_in,
                              void* d_out, int out_size, void* d_ws, size_t ws_size,
                              hipStream_t stream)
{
    const float* points = (const float*)d_in[0];   // (64,128,1,2)
    const float* dmap   = (const float*)d_in[1];   // (64,256,256,1)
    float* out          = (float*)d_out;
    uint4* partials     = (uint4*)d_ws;            // 1024 * 16 B

    fill_dice_kernel<<<dim3(NBLK), dim3(256), 0, stream>>>(points, dmap, partials);
    finalize_kernel<<<dim3(1), dim3(64), 0, stream>>>(partials, out);
}